// Round 7
// baseline (247.463 us; speedup 1.0000x reference)
//
#include <hip/hip_runtime.h>
#include <stdint.h>
#include <stddef.h>

typedef __bf16 bf16;
typedef __bf16 bf16x8 __attribute__((ext_vector_type(8)));
typedef __bf16 bf16x4 __attribute__((ext_vector_type(4)));
typedef __bf16 bf16x2 __attribute__((ext_vector_type(2)));
typedef float f32x4 __attribute__((ext_vector_type(4)));

static_assert(sizeof(bf16x8) == 16, "bf16x8 must be 16B");

__device__ __forceinline__ void gload_lds16(const void* g, void* l) {
    __builtin_amdgcn_global_load_lds(
        (const __attribute__((address_space(1))) uint32_t*)g,
        (__attribute__((address_space(3))) uint32_t*)l, 16, 0, 0);
}

// ---------------------------------------------------------------------------
// Kernel 1 (fused): attention (redundant per agg block) + weight aggregation
// (blocks 0..127) + x transpose (blocks 128..639).
//
// v7: the standalone attn kernel is ELIMINATED. Each agg block recomputes
// att[8][16] itself (pool + MLP + softmax, ~5us, bit-identical across blocks
// since the instruction sequence is identical). Saves one kernel-launch
// serialization gap (~13us, measured via r3's 4->3 launch fusion) plus the
// attn kernel's own time. w1 re-read = 128 x 614KB = 78MB of L3 traffic,
// hidden under the transpose blocks' memory phase.
//
// agg: block = (chunk(4), cog(32)) owns 8 consecutive co; per (b,pos,cg)
// writes a contiguous 128B piece -> full-line HBM writes.
// agg_w2 layout: [b][pos][chunk(4)][half(2)][cg(8)][co_l(128)][c8(8)]  bf16
// xt layout:     [b*64+y][cg(32)][x(64)][c8(8)]                        bf16
// ---------------------------------------------------------------------------
__global__ __launch_bounds__(256) void aggt_kernel(
    const float* __restrict__ weight,
    const float* __restrict__ bias,
    const float* __restrict__ sk,
    const float* __restrict__ w1,
    const float* __restrict__ w2,
    bf16* __restrict__ aggw,
    float* __restrict__ aggb,
    const float* __restrict__ x,
    bf16* __restrict__ xt) {
    __shared__ __align__(16) char smem[73984];
    const int t = threadIdx.x;

    if (blockIdx.x >= 128) {
        // ---- transpose block: x[b][ci][y][x] fp32 -> xt bf16 ----
        const int bid = blockIdx.x - 128;
        const int b = bid >> 6, y = bid & 63;
        bf16* T = (bf16*)smem;  // [ci(256)][x(64)]
        const float* src = x + (size_t)b * 256 * 4096 + (size_t)y * 64;
        for (int i = 0; i < 16; ++i) {
            int v = t + 256 * i;              // 4096 float4 chunks
            int ci = v >> 4, x4 = (v & 15) * 4;
            float4 f = *(const float4*)(src + (size_t)ci * 4096 + x4);
            bf16* d = &T[ci * 64 + x4];
            d[0] = (bf16)f.x; d[1] = (bf16)f.y; d[2] = (bf16)f.z; d[3] = (bf16)f.w;
        }
        __syncthreads();
        bf16* dstb = xt + (size_t)bid * 16384;
        for (int i = 0; i < 8; ++i) {
            int c2 = t + 256 * i;             // 2048 16B chunks: [cg][x]
            int cg = c2 >> 6, xx = c2 & 63;
            bf16x8 v;
#pragma unroll
            for (int c = 0; c < 8; ++c) v[c] = T[(cg * 8 + c) * 64 + xx];
            *(bf16x8*)(dstb + (size_t)c2 * 8) = v;
        }
        return;
    }

    // ======================= agg block =======================
    const int chunk = blockIdx.x >> 5, cog = blockIdx.x & 31;
    const int half = cog >> 4;

    // ---- phase A: recompute att[8][16] locally ----
    float* pooled_s = (float*)smem;            // [8][784] = 25088 B
    float* hdn_s = (float*)(smem + 25088);     // [8][196] =  6272 B
    __shared__ float att_s[8][16];

#pragma unroll
    for (int b = 0; b < 8; ++b) {
        const float* skb = sk + (size_t)b * 3136;
        for (int e = t; e < 784; e += 256) {
            int oy = e / 28, ox = e % 28;
            const float* p = skb + (oy * 2) * 56 + ox * 2;
            pooled_s[b * 784 + e] = 0.25f * (p[0] + p[1] + p[56] + p[57]);
        }
    }
    __syncthreads();
    {
        const int q = t & 15, g = t >> 4;  // 16 groups of 16 lanes
        for (int j = g; j < 196; j += 16) {
            float s[8];
#pragma unroll
            for (int b = 0; b < 8; ++b) s[b] = 0.f;
            const float* wr = w1 + (size_t)j * 784 + q;
            for (int i = 0; i < 49; ++i) {
                const float wv = wr[i * 16];
                const int idx = q + i * 16;
#pragma unroll
                for (int b = 0; b < 8; ++b) s[b] += pooled_s[b * 784 + idx] * wv;
            }
#pragma unroll
            for (int off = 8; off; off >>= 1)
#pragma unroll
                for (int b = 0; b < 8; ++b) s[b] += __shfl_xor(s[b], off, 16);
            if (q == 0)
#pragma unroll
                for (int b = 0; b < 8; ++b) hdn_s[b * 196 + j] = s[b] > 0.f ? s[b] : 0.f;
        }
    }
    __syncthreads();
    if (t < 128) {
        const int b = t >> 4, k = t & 15;
        float s = 0.f;
        const float* wr = w2 + (size_t)k * 196;
        for (int j = 0; j < 196; ++j) s += hdn_s[b * 196 + j] * wr[j];
        float l = s * (1.0f / 30.0f);
        float m = l;
#pragma unroll
        for (int off = 8; off; off >>= 1) m = fmaxf(m, __shfl_xor(m, off, 16));
        float e = expf(l - m);
        float sum = e;
#pragma unroll
        for (int off = 8; off; off >>= 1) sum += __shfl_xor(sum, off, 16);
        att_s[b][k] = e / sum;
    }
    __syncthreads();  // att_s ready; pooled/hdn dead -> smem reused as accW

    bf16* accW = (bf16*)smem;  // [co_i(8)][b(8)][e(stride 578)]

    if (chunk == 0 && t < 64) {
        const int b = t >> 3, co = cog * 8 + (t & 7);
        float s = 0.f;
        for (int k = 0; k < 16; ++k) s += att_s[b][k] * bias[k * 256 + co];
        aggb[b * 256 + co] = s;
    }

    // 2304 float2-tasks: id -> co_i = id/288, e2 = id%288 (elems 2e2,2e2+1)
#pragma unroll
    for (int r = 0; r < 9; ++r) {
        const int id = t + 256 * r;
        const int co_i = id / 288, e2 = id - co_i * 288;
        const int co = cog * 8 + co_i;
        const float* wbase = weight + (size_t)co * 2304 + (size_t)chunk * 576 + 2 * e2;
        float2 wv[16];
#pragma unroll
        for (int k = 0; k < 16; ++k)
            wv[k] = *(const float2*)(wbase + (size_t)k * 589824);
        float a[8][2];
#pragma unroll
        for (int b = 0; b < 8; ++b) { a[b][0] = 0.f; a[b][1] = 0.f; }
#pragma unroll
        for (int k = 0; k < 16; ++k) {
#pragma unroll
            for (int b = 0; b < 8; ++b) {
                const float av = att_s[b][k];
                a[b][0] += av * wv[k].x;
                a[b][1] += av * wv[k].y;
            }
        }
#pragma unroll
        for (int b = 0; b < 8; ++b) {
            bf16x2 v; v[0] = (bf16)a[b][0]; v[1] = (bf16)a[b][1];
            *(bf16x2*)&accW[(co_i * 8 + b) * 578 + 2 * e2] = v;
        }
    }
    __syncthreads();

    // write-out: 4608 16B stores; piece (b,pos,cg) = contiguous 128B of aggw
    const int cogl = cog & 15;
#pragma unroll
    for (int i = 0; i < 18; ++i) {
        const int s = t + 256 * i;
        const int piece = s >> 3, sub = s & 7;
        const int b = piece / 72, r = piece - b * 72;
        const int pos = r >> 3, cg = r & 7;
        bf16x8 v;
#pragma unroll
        for (int c = 0; c < 8; ++c)
            v[c] = accW[(sub * 8 + b) * 578 + (cg * 8 + c) * 9 + pos];
        const size_t G = ((((size_t)b * 9 + pos) * 4 + chunk) * 2 + half) * 8 + cg;
        *(bf16x8*)(aggw + G * 1024 + cogl * 64 + sub * 8) = v;
    }
}

// ---------------------------------------------------------------------------
// Kernel 2: implicit-GEMM conv + bias + residual.  (r6 version, unchanged —
// measured 48.2us, MfmaUtil 31%, FETCH 37.5MB with the XCD swizzle)
// grid = 512: bid = ytile*16 + (b*2+half); 2 blocks/CU hide per-tap drains.
// ---------------------------------------------------------------------------
__global__ __launch_bounds__(256, 2) void conv_kernel(
    const bf16* __restrict__ xt, const bf16* __restrict__ aggw,
    const float* __restrict__ aggb, const float* __restrict__ xin,
    float* __restrict__ out) {
    const int bid = blockIdx.x;
    const int slice = bid & 15, ytile = bid >> 4;
    const int b = slice >> 1, half = slice & 1;
    const int tid = threadIdx.x;
    const int wave = tid >> 6, lane = tid & 63;
    const int wm = wave & 1, wn = wave >> 1;
    const int lane15 = lane & 15, quad = lane >> 4;

    __shared__ __align__(16) bf16 Xs[4][8][66][8];  // [row][cg][col(padded)][c8]
    __shared__ __align__(16) bf16 Ws[8][128][8];    // [cg][co_l][c8]

    f32x4 acc[4][4];
#pragma unroll
    for (int mt = 0; mt < 4; ++mt)
#pragma unroll
        for (int nt = 0; nt < 4; ++nt) acc[mt][nt] = f32x4{0.f, 0.f, 0.f, 0.f};

    // zero the whole X tile once: halo cols 0/65 and out-of-image rows stay 0.
    {
        uint4 z; z.x = z.y = z.z = z.w = 0u;
        uint4* p = (uint4*)&Xs[0][0][0][0];
        for (int i = tid; i < 2112; i += 256) p[i] = z;
    }

    const int yrow = ytile * 2 - 1 + wave;          // wave w stages halo row w
    const bool rowok = (yrow >= 0) && (yrow < 64);
    const bf16* xsrc = xt + ((size_t)b * 64 + (rowok ? yrow : 0)) * 16384 + (size_t)lane * 8;
    bf16* xdstbase = &Xs[wave][0][1][0];            // +cg*528 per cg

    for (int chunk = 0; chunk < 4; ++chunk) {
        __syncthreads();                            // prev compute done (and zero-fill)
        if (rowok) {
            const bf16* s0 = xsrc + (size_t)chunk * 4096;
#pragma unroll
            for (int cg = 0; cg < 8; ++cg)
                gload_lds16(s0 + cg * 512, xdstbase + cg * 528);
        }
        const bf16* wchunkbase = aggw + (((size_t)b * 36 + chunk) * 2 + half) * 8192;
        for (int pos = 0; pos < 9; ++pos) {
            if (pos) __syncthreads();               // prev tap done reading Ws
            const bf16* wsrc = wchunkbase + (size_t)pos * 65536 + wave * 2048 + (size_t)lane * 8;
            bf16* wdst = ((bf16*)Ws) + wave * 2048;
#pragma unroll
            for (int i = 0; i < 4; ++i)
                gload_lds16(wsrc + i * 512, wdst + i * 512);
            __syncthreads();                        // drains vmcnt (global_load_lds)
            const int kh = pos / 3, kw = pos - kh * 3;
            const int xr = wn + kh;
#pragma unroll
            for (int s = 0; s < 2; ++s) {
                const int cg = s * 4 + quad;
                bf16x8 afr[4], bfr[4];
#pragma unroll
                for (int mt = 0; mt < 4; ++mt)
                    afr[mt] = *(const bf16x8*)&Ws[cg][wm * 64 + mt * 16 + lane15][0];
#pragma unroll
                for (int nt = 0; nt < 4; ++nt)
                    bfr[nt] = *(const bf16x8*)&Xs[xr][cg][kw + nt * 16 + lane15][0];
#pragma unroll
                for (int mt = 0; mt < 4; ++mt)
#pragma unroll
                    for (int nt = 0; nt < 4; ++nt)
                        acc[mt][nt] = __builtin_amdgcn_mfma_f32_16x16x32_bf16(
                            afr[mt], bfr[nt], acc[mt][nt], 0, 0, 0);
            }
        }
    }

    // epilogue: conv + agg_b + residual, fp32 out
    const int y = ytile * 2 + wn;
#pragma unroll
    for (int mt = 0; mt < 4; ++mt) {
#pragma unroll
        for (int r = 0; r < 4; ++r) {
            const int co = half * 128 + wm * 64 + mt * 16 + quad * 4 + r;
            const float bbv = aggb[b * 256 + co];
            const size_t rowbase = (((size_t)b * 256 + co) * 64 + y) * 64;
#pragma unroll
            for (int nt = 0; nt < 4; ++nt) {
                const size_t oidx = rowbase + nt * 16 + lane15;
                out[oidx] = acc[mt][nt][r] + bbv + xin[oidx];
            }
        }
    }
}

// ---------------------------------------------------------------------------
extern "C" void kernel_launch(void* const* d_in, const int* in_sizes, int n_in,
                              void* d_out, int out_size, void* d_ws, size_t ws_size,
                              hipStream_t stream) {
    const float* x    = (const float*)d_in[0];  // [8,256,64,64]
    const float* sk   = (const float*)d_in[1];  // [8,1,56,56]
    const float* wgt  = (const float*)d_in[2];  // [16,256,256,3,3]
    const float* bias = (const float*)d_in[3];  // [16,256]
    const float* w1   = (const float*)d_in[4];  // [196,784]
    const float* w2   = (const float*)d_in[5];  // [16,196]
    float* out = (float*)d_out;

    char* ws = (char*)d_ws;
    float* aggb = (float*)(ws + 1024);                   // 8 KB
    bf16*  aggw = (bf16*)(ws + 16384);                   // 9,437,184 B
    bf16*  xt   = (bf16*)(ws + 16384 + 9437184);         // 16,777,216 B

    aggt_kernel<<<640, 256, 0, stream>>>(wgt, bias, sk, w1, w2, aggw, aggb, x, xt);
    conv_kernel<<<512, 256, 0, stream>>>(xt, aggw, aggb, x, out);
}

// Round 8
// 171.574 us; speedup vs baseline: 1.4423x; 1.4423x over previous
//
#include <hip/hip_runtime.h>
#include <stdint.h>
#include <stddef.h>

typedef __bf16 bf16;
typedef __bf16 bf16x8 __attribute__((ext_vector_type(8)));
typedef __bf16 bf16x4 __attribute__((ext_vector_type(4)));
typedef __bf16 bf16x2 __attribute__((ext_vector_type(2)));
typedef float f32x4 __attribute__((ext_vector_type(4)));

static_assert(sizeof(bf16x8) == 16, "bf16x8 must be 16B");

__device__ __forceinline__ void gload_lds16(const void* g, void* l) {
    __builtin_amdgcn_global_load_lds(
        (const __attribute__((address_space(1))) uint32_t*)g,
        (__attribute__((address_space(3))) uint32_t*)l, 16, 0, 0);
}

// ---------------------------------------------------------------------------
// Kernel 1: attention  (pool 56x56 -> 28x28, MLP 784->196->16, softmax/T)
// grid = 8, block = 1024.
// v8: GEMV1 is wave-per-row — 12 x 256B fully-coalesced w1 loads per row,
// deep MLP, 64-lane shfl reduce (was 16-lane groups reading 64B segments).
// ---------------------------------------------------------------------------
__global__ __launch_bounds__(1024) void attn_kernel(const float* __restrict__ sk,
                                                    const float* __restrict__ w1,
                                                    const float* __restrict__ w2,
                                                    float* __restrict__ att) {
    const int b = blockIdx.x, t = threadIdx.x;
    __shared__ float pooled[784];
    __shared__ float hdn[196];
    __shared__ float logits[16];
    const float* skb = sk + (size_t)b * 3136;
    if (t < 784) {
        int oy = t / 28, ox = t % 28;
        const float* p = skb + (oy * 2) * 56 + ox * 2;
        pooled[t] = 0.25f * (p[0] + p[1] + p[56] + p[57]);
    }
    __syncthreads();
    {
        const int wv = t >> 6, ln = t & 63;   // 16 waves
        for (int j = wv; j < 196; j += 16) {
            const float* wr = w1 + (size_t)j * 784;
            float s = 0.f;
#pragma unroll
            for (int i = 0; i < 12; ++i) s += pooled[ln + 64 * i] * wr[ln + 64 * i];
            if (ln < 16) s += pooled[768 + ln] * wr[768 + ln];
#pragma unroll
            for (int off = 32; off; off >>= 1) s += __shfl_xor(s, off, 64);
            if (ln == 0) hdn[j] = s > 0.f ? s : 0.f;
        }
    }
    __syncthreads();
    if (t < 256) {
        const int jj = t >> 4, qq = t & 15;
        float s = 0.f;
#pragma unroll
        for (int i = 0; i < 13; ++i) {
            const int idx = qq + i * 16;
            if (idx < 196) s += hdn[idx] * w2[jj * 196 + idx];
        }
#pragma unroll
        for (int off = 8; off; off >>= 1) s += __shfl_xor(s, off, 16);
        if (qq == 0) logits[jj] = s * (1.0f / 30.0f);
    }
    __syncthreads();
    if (t == 0) {
        float m = logits[0];
        for (int k = 1; k < 16; ++k) m = fmaxf(m, logits[k]);
        float e16[16], sum = 0.f;
        for (int k = 0; k < 16; ++k) { e16[k] = expf(logits[k] - m); sum += e16[k]; }
        float inv = 1.f / sum;
        for (int k = 0; k < 16; ++k) att[b * 16 + k] = e16[k] * inv;
    }
}

// ---------------------------------------------------------------------------
// Kernel 2 (fused): agg (blocks 0..255) + x transpose (blocks 256..767).
//
// v8 agg: split each r6 agg block in two along the cg axis (e-range
// [0,288)/[288,576) maps exactly to cg 0..3 / 4..7). 256 blocks; static
// smem drops 74 -> 37.1 KB  => 4 blocks/CU (was 2) for BOTH paths. The agg
// work was measured latency-bound (r7: VALUBusy 7%, occ 6%) -- occupancy is
// the lever. Write pattern keeps full-line 128B pieces; numerics identical.
// agg_w2 layout: [b][pos][chunk(4)][half(2)][cg(8)][co_l(128)][c8(8)]  bf16
// xt layout:     [b*64+y][cg(32)][x(64)][c8(8)]                        bf16
// ---------------------------------------------------------------------------
__global__ __launch_bounds__(256, 4) void aggt_kernel(
    const float* __restrict__ weight,
    const float* __restrict__ bias,
    const float* __restrict__ att,
    bf16* __restrict__ aggw,
    float* __restrict__ aggb,
    const float* __restrict__ x,
    bf16* __restrict__ xt) {
    __shared__ __align__(16) char smem[37120];
    const int t = threadIdx.x;

    if (blockIdx.x >= 256) {
        // ---- transpose block: x[b][ci][y][x] fp32 -> xt bf16 ----
        const int bid = blockIdx.x - 256;
        const int b = bid >> 6, y = bid & 63;
        bf16* T = (bf16*)smem;  // [ci(256)][x(64)]  32 KB
        const float* src = x + (size_t)b * 256 * 4096 + (size_t)y * 64;
        for (int i = 0; i < 16; ++i) {
            int v = t + 256 * i;              // 4096 float4 chunks
            int ci = v >> 4, x4 = (v & 15) * 4;
            float4 f = *(const float4*)(src + (size_t)ci * 4096 + x4);
            bf16* d = &T[ci * 64 + x4];
            d[0] = (bf16)f.x; d[1] = (bf16)f.y; d[2] = (bf16)f.z; d[3] = (bf16)f.w;
        }
        __syncthreads();
        bf16* dstb = xt + (size_t)bid * 16384;
        for (int i = 0; i < 8; ++i) {
            int c2 = t + 256 * i;             // 2048 16B chunks: [cg][x]
            int cg = c2 >> 6, xx = c2 & 63;
            bf16x8 v;
#pragma unroll
            for (int c = 0; c < 8; ++c) v[c] = T[(cg * 8 + c) * 64 + xx];
            *(bf16x8*)(dstb + (size_t)c2 * 8) = v;
        }
        return;
    }

    // ---- agg block: chunkq = bid>>5 (chunk(4) x cghalf(2)), cog = bid&31 ----
    const int chunkq = blockIdx.x >> 5, cog = blockIdx.x & 31;
    const int chunk = chunkq >> 1, cghalf = chunkq & 1;
    const int half = cog >> 4, cogl = cog & 15;
    bf16* accW = (bf16*)smem;  // [co_i(8)*8+b][e(stride 290)]  37.1 KB

    if (chunkq == 0 && t < 64) {
        const int b = t >> 3, co = cog * 8 + (t & 7);
        float s = 0.f;
        for (int k = 0; k < 16; ++k) s += att[b * 16 + k] * bias[k * 256 + co];
        aggb[b * 256 + co] = s;
    }

    // 1152 float2-tasks: id -> co_i = id/144, e2 = id%144 (elems 2e2,2e2+1)
    for (int r = 0; r < 5; ++r) {
        const int id = t + 256 * r;
        if (id < 1152) {
            const int co_i = id / 144, e2 = id - co_i * 144;
            const int co = cog * 8 + co_i;
            const float* wbase = weight + (size_t)co * 2304 + (size_t)chunk * 576
                               + cghalf * 288 + 2 * e2;
            float2 wv[16];
#pragma unroll
            for (int k = 0; k < 16; ++k)
                wv[k] = *(const float2*)(wbase + (size_t)k * 589824);
            float a[8][2];
#pragma unroll
            for (int b = 0; b < 8; ++b) { a[b][0] = 0.f; a[b][1] = 0.f; }
#pragma unroll
            for (int k = 0; k < 16; ++k) {
#pragma unroll
                for (int b = 0; b < 8; ++b) {
                    const float av = att[b * 16 + k];  // uniform -> scalar load
                    a[b][0] += av * wv[k].x;
                    a[b][1] += av * wv[k].y;
                }
            }
#pragma unroll
            for (int b = 0; b < 8; ++b) {
                bf16x2 v; v[0] = (bf16)a[b][0]; v[1] = (bf16)a[b][1];
                *(bf16x2*)&accW[(co_i * 8 + b) * 290 + 2 * e2] = v;
            }
        }
    }
    __syncthreads();

    // write-out: 2304 16B stores; piece (b,pos,cg) = contiguous 128B of aggw
#pragma unroll
    for (int i = 0; i < 9; ++i) {
        const int s = t + 256 * i;
        const int piece = s >> 3, sub = s & 7;          // sub = co_i
        const int b = piece / 36, r2 = piece - b * 36;  // 36 = 9 pos x 4 cg_loc
        const int pos = r2 >> 2, cg_loc = r2 & 3;
        bf16x8 v;
#pragma unroll
        for (int c = 0; c < 8; ++c)
            v[c] = accW[(sub * 8 + b) * 290 + (cg_loc * 8 + c) * 9 + pos];
        const size_t G = ((((size_t)b * 9 + pos) * 4 + chunk) * 2 + half) * 8
                       + cghalf * 4 + cg_loc;
        *(bf16x8*)(aggw + G * 1024 + cogl * 64 + sub * 8) = v;
    }
}

// ---------------------------------------------------------------------------
// Kernel 3: implicit-GEMM conv + bias + residual.  (r6 version, unchanged —
// measured 48.2us, MfmaUtil 31%, FETCH 37.5MB with the XCD swizzle)
// grid = 512: bid = ytile*16 + (b*2+half); 2 blocks/CU hide per-tap drains.
// ---------------------------------------------------------------------------
__global__ __launch_bounds__(256, 2) void conv_kernel(
    const bf16* __restrict__ xt, const bf16* __restrict__ aggw,
    const float* __restrict__ aggb, const float* __restrict__ xin,
    float* __restrict__ out) {
    const int bid = blockIdx.x;
    const int slice = bid & 15, ytile = bid >> 4;
    const int b = slice >> 1, half = slice & 1;
    const int tid = threadIdx.x;
    const int wave = tid >> 6, lane = tid & 63;
    const int wm = wave & 1, wn = wave >> 1;
    const int lane15 = lane & 15, quad = lane >> 4;

    __shared__ __align__(16) bf16 Xs[4][8][66][8];  // [row][cg][col(padded)][c8]
    __shared__ __align__(16) bf16 Ws[8][128][8];    // [cg][co_l][c8]

    f32x4 acc[4][4];
#pragma unroll
    for (int mt = 0; mt < 4; ++mt)
#pragma unroll
        for (int nt = 0; nt < 4; ++nt) acc[mt][nt] = f32x4{0.f, 0.f, 0.f, 0.f};

    // zero the whole X tile once: halo cols 0/65 and out-of-image rows stay 0.
    {
        uint4 z; z.x = z.y = z.z = z.w = 0u;
        uint4* p = (uint4*)&Xs[0][0][0][0];
        for (int i = tid; i < 2112; i += 256) p[i] = z;
    }

    const int yrow = ytile * 2 - 1 + wave;          // wave w stages halo row w
    const bool rowok = (yrow >= 0) && (yrow < 64);
    const bf16* xsrc = xt + ((size_t)b * 64 + (rowok ? yrow : 0)) * 16384 + (size_t)lane * 8;
    bf16* xdstbase = &Xs[wave][0][1][0];            // +cg*528 per cg

    for (int chunk = 0; chunk < 4; ++chunk) {
        __syncthreads();                            // prev compute done (and zero-fill)
        if (rowok) {
            const bf16* s0 = xsrc + (size_t)chunk * 4096;
#pragma unroll
            for (int cg = 0; cg < 8; ++cg)
                gload_lds16(s0 + cg * 512, xdstbase + cg * 528);
        }
        const bf16* wchunkbase = aggw + (((size_t)b * 36 + chunk) * 2 + half) * 8192;
        for (int pos = 0; pos < 9; ++pos) {
            if (pos) __syncthreads();               // prev tap done reading Ws
            const bf16* wsrc = wchunkbase + (size_t)pos * 65536 + wave * 2048 + (size_t)lane * 8;
            bf16* wdst = ((bf16*)Ws) + wave * 2048;
#pragma unroll
            for (int i = 0; i < 4; ++i)
                gload_lds16(wsrc + i * 512, wdst + i * 512);
            __syncthreads();                        // drains vmcnt (global_load_lds)
            const int kh = pos / 3, kw = pos - kh * 3;
            const int xr = wn + kh;
#pragma unroll
            for (int s = 0; s < 2; ++s) {
                const int cg = s * 4 + quad;
                bf16x8 afr[4], bfr[4];
#pragma unroll
                for (int mt = 0; mt < 4; ++mt)
                    afr[mt] = *(const bf16x8*)&Ws[cg][wm * 64 + mt * 16 + lane15][0];
#pragma unroll
                for (int nt = 0; nt < 4; ++nt)
                    bfr[nt] = *(const bf16x8*)&Xs[xr][cg][kw + nt * 16 + lane15][0];
#pragma unroll
                for (int mt = 0; mt < 4; ++mt)
#pragma unroll
                    for (int nt = 0; nt < 4; ++nt)
                        acc[mt][nt] = __builtin_amdgcn_mfma_f32_16x16x32_bf16(
                            afr[mt], bfr[nt], acc[mt][nt], 0, 0, 0);
            }
        }
    }

    // epilogue: conv + agg_b + residual, fp32 out
    const int y = ytile * 2 + wn;
#pragma unroll
    for (int mt = 0; mt < 4; ++mt) {
#pragma unroll
        for (int r = 0; r < 4; ++r) {
            const int co = half * 128 + wm * 64 + mt * 16 + quad * 4 + r;
            const float bbv = aggb[b * 256 + co];
            const size_t rowbase = (((size_t)b * 256 + co) * 64 + y) * 64;
#pragma unroll
            for (int nt = 0; nt < 4; ++nt) {
                const size_t oidx = rowbase + nt * 16 + lane15;
                out[oidx] = acc[mt][nt][r] + bbv + xin[oidx];
            }
        }
    }
}

// ---------------------------------------------------------------------------
extern "C" void kernel_launch(void* const* d_in, const int* in_sizes, int n_in,
                              void* d_out, int out_size, void* d_ws, size_t ws_size,
                              hipStream_t stream) {
    const float* x    = (const float*)d_in[0];  // [8,256,64,64]
    const float* sk   = (const float*)d_in[1];  // [8,1,56,56]
    const float* wgt  = (const float*)d_in[2];  // [16,256,256,3,3]
    const float* bias = (const float*)d_in[3];  // [16,256]
    const float* w1   = (const float*)d_in[4];  // [196,784]
    const float* w2   = (const float*)d_in[5];  // [16,196]
    float* out = (float*)d_out;

    char* ws = (char*)d_ws;
    float* att  = (float*)(ws + 0);                      // 512 B
    float* aggb = (float*)(ws + 1024);                   // 8 KB
    bf16*  aggw = (bf16*)(ws + 16384);                   // 9,437,184 B
    bf16*  xt   = (bf16*)(ws + 16384 + 9437184);         // 16,777,216 B

    attn_kernel<<<8, 1024, 0, stream>>>(sk, w1, w2, att);
    aggt_kernel<<<768, 256, 0, stream>>>(wgt, bias, att, aggw, aggb, x, xt);
    conv_kernel<<<512, 256, 0, stream>>>(xt, aggw, aggb, x, out);
}